// Round 9
// baseline (261.643 us; speedup 1.0000x reference)
//
#include <hip/hip_runtime.h>
#include <hip/hip_bf16.h>
#include <cstdint>

#define NB 4
#define NQ 512
#define NM 8192
#define NH 8
#define DH 64

typedef short bf16x8s __attribute__((ext_vector_type(8)));
typedef float f32x4  __attribute__((ext_vector_type(4)));

// fast fp32->bf16 (round-half-up)
static __device__ __forceinline__ short f2bs(float f) {
    unsigned u = __builtin_bit_cast(unsigned, f);
    return (short)(unsigned short)((u + 0x8000u) >> 16);
}
// packed pair via v_perm_b32: lo16 = bf16(a), hi16 = bf16(b)
static __device__ __forceinline__ unsigned pk2(float a, float b) {
    unsigned au = __builtin_bit_cast(unsigned, a) + 0x8000u;
    unsigned bu = __builtin_bit_cast(unsigned, b) + 0x8000u;
    return __builtin_amdgcn_perm(bu, au, 0x07060302u);
}

#if __has_builtin(__builtin_amdgcn_exp2f)
static __device__ __forceinline__ float fexp2(float x) { return __builtin_amdgcn_exp2f(x); }
#else
static __device__ __forceinline__ float fexp2(float x) { return exp2f(x); }
#endif

// ---------------------------------------------------------------------------
// Weight prep: Wq/Wo [512,512], Wkv [256,1024] (fp32 [k][n]) -> bf16 MFMA
// B-fragment order: Wf[(n0*KS + ks)*64 + lane][j] = W[ks*32+quad*8+j][n0*16+m16]
// ---------------------------------------------------------------------------
__global__ __launch_bounds__(256) void prep_weights(
    const float* __restrict__ Wq, const float* __restrict__ Wo,
    const float* __restrict__ Wkv,
    short* __restrict__ Wqf, short* __restrict__ Wof, short* __restrict__ Wkvf)
{
    const int t = threadIdx.x;
    const int w = t >> 6, ln = t & 63;
    const int m16 = ln & 15, quad = ln >> 4;
    int f = blockIdx.x * 4 + w;           // 0..1535
    const float* src; short* dst; int N, KS, n0, ks;
    if (f < 512)       { src = Wq;  dst = Wqf;  N = 512;  KS = 16; n0 = f >> 4; ks = f & 15; }
    else if (f < 1024) { f -= 512;  src = Wo;  dst = Wof;  N = 512;  KS = 16; n0 = f >> 4; ks = f & 15; }
    else               { f -= 1024; src = Wkv; dst = Wkvf; N = 1024; KS = 8;  n0 = f >> 3; ks = f & 7; }
    const float* sp = src + (size_t)(ks * 32 + quad * 8) * N + n0 * 16 + m16;
    float v[8];
    #pragma unroll
    for (int j = 0; j < 8; ++j) v[j] = sp[(size_t)j * N];
    uint4 pkv = { pk2(v[0],v[1]), pk2(v[2],v[3]), pk2(v[4],v[5]), pk2(v[6],v[7]) };
    *(uint4*)(dst + ((size_t)(n0 * KS + ks) * 64 + ln) * 8) = pkv;
}

// ---------------------------------------------------------------------------
// q-projection body (barrier-free, no LDS): q[2048,512] = x @ Wq.
// 32x64 tile; A-frags direct from global (16 full cache lines per wave-load),
// B-frags from fragment-order weights. 512 blocks.
// ---------------------------------------------------------------------------
__device__ __forceinline__ void proj_q_body(
    const float* __restrict__ A, const short* __restrict__ Wf,
    float* __restrict__ C, int tm, int tn)
{
    const int t = threadIdx.x;
    const int w = t >> 6, ln = t & 63;
    const int m16 = ln & 15, quad = ln >> 4;
    const int wm = w >> 1, wn = w & 1;

    const int row = tm * 32 + wm * 16 + m16;
    const float* Ap = A + (size_t)row * 512 + quad * 8;

    f32x4 acc[2] = {};

    for (int k0 = 0; k0 < 512; k0 += 64) {
        #pragma unroll
        for (int ks = 0; ks < 2; ++ks) {
            float4 a0 = *(const float4*)(Ap + k0 + ks * 32);
            float4 a1 = *(const float4*)(Ap + k0 + ks * 32 + 4);
            uint4 wa = { pk2(a0.x,a0.y), pk2(a0.z,a0.w), pk2(a1.x,a1.y), pk2(a1.z,a1.w) };
            bf16x8s af = *reinterpret_cast<bf16x8s*>(&wa);
            #pragma unroll
            for (int nt = 0; nt < 2; ++nt) {
                bf16x8s bf = *(const bf16x8s*)(Wf +
                    ((size_t)((tn * 4 + wn * 2 + nt) * 16 + (k0 >> 5) + ks) * 64 + ln) * 8);
                acc[nt] = __builtin_amdgcn_mfma_f32_16x16x32_bf16(af, bf, acc[nt], 0, 0, 0);
            }
        }
    }

    const int row0 = tm * 32 + wm * 16 + quad * 4;
    const int col0 = tn * 64 + wn * 32;
    #pragma unroll
    for (int nt = 0; nt < 2; ++nt) {
        const int col = col0 + nt * 16 + m16;
        #pragma unroll
        for (int r = 0; r < 4; ++r)
            C[(size_t)(row0 + r) * 512 + col] = acc[nt][r];
    }
}

// ---------------------------------------------------------------------------
// kv body (barrier-free, no LDS): 128(m) x 128(n) tile, BK=32, K=256.
// 4 waves each own 32 rows x 128 cols. A-frags direct from global,
// B-frags from fragment-order Wkv. Fragment-order K/V epilogue.
// tm = bid&255 keeps the 8 n-tiles of an m-tile on one XCD.
// ---------------------------------------------------------------------------
__device__ __forceinline__ void kv_body(
    const float* __restrict__ A, const short* __restrict__ Wkvf,
    short* __restrict__ Kf, short* __restrict__ Vf, int bid)
{
    const int t  = threadIdx.x;
    const int tm = bid & 255, tn = bid >> 8;
    const int w  = t >> 6, ln = t & 63;
    const int m16 = ln & 15, quad = ln >> 4;

    const float* Ap0 = A + (size_t)(tm * 128 + w * 32 + m16) * 256 + quad * 8;
    const float* Ap1 = Ap0 + 16 * 256;

    f32x4 acc[2][8] = {};

    for (int k0 = 0; k0 < 256; k0 += 32) {
        bf16x8s af[2];
        {
            float4 a0 = *(const float4*)(Ap0 + k0);
            float4 a1 = *(const float4*)(Ap0 + k0 + 4);
            uint4 wa = { pk2(a0.x,a0.y), pk2(a0.z,a0.w), pk2(a1.x,a1.y), pk2(a1.z,a1.w) };
            af[0] = *reinterpret_cast<bf16x8s*>(&wa);
            float4 b0 = *(const float4*)(Ap1 + k0);
            float4 b1 = *(const float4*)(Ap1 + k0 + 4);
            uint4 wb = { pk2(b0.x,b0.y), pk2(b0.z,b0.w), pk2(b1.x,b1.y), pk2(b1.z,b1.w) };
            af[1] = *reinterpret_cast<bf16x8s*>(&wb);
        }
        #pragma unroll
        for (int j = 0; j < 8; ++j) {
            bf16x8s bfr = *(const bf16x8s*)(Wkvf +
                ((size_t)((tn * 8 + j) * 8 + (k0 >> 5)) * 64 + ln) * 8);
            acc[0][j] = __builtin_amdgcn_mfma_f32_16x16x32_bf16(af[0], bfr, acc[0][j], 0, 0, 0);
            acc[1][j] = __builtin_amdgcn_mfma_f32_16x16x32_bf16(af[1], bfr, acc[1][j], 0, 0, 0);
        }
    }

    const int row0 = tm * 128 + w * 32;
    const int b    = row0 >> 13;
    const int mr0  = row0 & (NM - 1);

    if (tn < 4) {   // all K columns
        #pragma unroll
        for (int j = 0; j < 8; ++j) {
            const int h = tn * 2 + (j >> 2);
            const int d = (j & 3) * 16 + m16;
            short* Kp = Kf + (size_t)(b * NH + h) * (NM * DH);
            #pragma unroll
            for (int i = 0; i < 2; ++i)
                #pragma unroll
                for (int r = 0; r < 4; ++r) {
                    const int key = mr0 + i * 16 + quad * 4 + r;
                    const int idx = ((key >> 4) * 2 + (d >> 5)) * 512
                                  + (((d >> 3) & 3) * 16 + (key & 15)) * 8 + (d & 7);
                    Kp[idx] = f2bs(acc[i][j][r]);
                }
        }
    } else {        // all V columns
        #pragma unroll
        for (int j = 0; j < 8; ++j) {
            const int h = (tn - 4) * 2 + (j >> 2);
            const int jj = j & 3;
            short* Vp = Vf + (size_t)(b * NH + h) * (NM * DH);
            #pragma unroll
            for (int i = 0; i < 2; ++i) {
                const int key0 = mr0 + i * 16 + quad * 4;
                const int idx = (jj * 256 + (key0 >> 5)) * 512
                              + ((((key0 >> 3) & 3) * 16 + m16) * 8) + (key0 & 7);
                uint2 pk;
                pk.x = pk2(acc[i][j][0], acc[i][j][1]);
                pk.y = pk2(acc[i][j][2], acc[i][j][3]);
                *(uint2*)(Vp + idx) = pk;
            }
        }
    }
}

// ---------------------------------------------------------------------------
// Uber kernel: blocks 0..511 -> q = x@Wq, blocks 512..2559 -> kv.
// No LDS, no barriers anywhere.
// ---------------------------------------------------------------------------
__global__ __launch_bounds__(256) void gemm_kvq(
    const float* __restrict__ x,   const short* __restrict__ Wqf, float* __restrict__ q,
    const float* __restrict__ ctx, const short* __restrict__ Wkvf,
    short* __restrict__ Kf, short* __restrict__ Vf)
{
    if (blockIdx.x < 512)
        proj_q_body(x, Wqf, q, (int)(blockIdx.x >> 3), (int)(blockIdx.x & 7));
    else
        kv_body(ctx, Wkvf, Kf, Vf, (int)(blockIdx.x - 512));
}

// ---------------------------------------------------------------------------
// Flash attention: zero LDS, zero barriers. Block = (bh, qt: 128 q-rows,
// kq: 2048-key quarter); 4 waves own 32 distinct q-rows each over the SAME
// keys (K/V frags shared via L1). S^T formulation, exp2-domain no-max
// softmax, l via ones-MFMA -> global atomicAdd. Unnormalized partial O
// written per quarter; out-proj merges.
// ---------------------------------------------------------------------------
__global__ __launch_bounds__(256) void attn_mfma(
    const float* __restrict__ Q,    // [2048, 512] fp32
    const short* __restrict__ Kfr,  // fragment-order K
    const short* __restrict__ Vfr,  // fragment-order V
    float* __restrict__ Po,         // [4][2048][512] partial O
    float* __restrict__ Lg)         // [B*H][512] softmax sums (atomic)
{
    const int bid = blockIdx.x;
    const int xcd = bid & 7, g = bid >> 3;
    const int bh  = xcd * 4 + (g & 3);
    const int qt  = (g >> 2) & 3;
    const int kq  = g >> 4;
    const int b   = bh >> 3, h = bh & 7;
    const int t   = threadIdx.x;
    const int w   = t >> 6, ln = t & 63;
    const int m16 = ln & 15, quad = ln >> 4;

    const short* Kbase = Kfr + (size_t)bh * (NM * DH);
    const short* Vbase = Vfr + (size_t)bh * (NM * DH);

    // Q scaled by (1/8) * log2(e)
    const float qsc = 0.125f * 1.44269504f;
    bf16x8s qf[2][2];
    #pragma unroll
    for (int mt = 0; mt < 2; ++mt) {
        const float* qrow = Q + ((size_t)(b * NQ + qt * 128 + w * 32 + mt * 16 + m16)) * 512 + h * 64;
        #pragma unroll
        for (int ks = 0; ks < 2; ++ks) {
            float4 x0 = *(const float4*)(qrow + ks * 32 + quad * 8);
            float4 x1 = *(const float4*)(qrow + ks * 32 + quad * 8 + 4);
            uint4 pkv = { pk2(x0.x * qsc, x0.y * qsc), pk2(x0.z * qsc, x0.w * qsc),
                          pk2(x1.x * qsc, x1.y * qsc), pk2(x1.z * qsc, x1.w * qsc) };
            qf[mt][ks] = *reinterpret_cast<bf16x8s*>(&pkv);
        }
    }

    bf16x8s ones;
    #pragma unroll
    for (int j = 0; j < 8; ++j) ones[j] = (short)0x3F80;

    f32x4 o[2][4] = {};
    f32x4 lsum[2] = {};

    const int srcLo = (((quad << 1) & 3) << 4) + m16;
    const int srcHi = ((((quad << 1) + 1) & 3) << 4) + m16;
    const bool ktHi = quad >= 2;

    bf16x8s kf[4][2];
    {
        const int kc = kq * 2048;
        #pragma unroll
        for (int nt = 0; nt < 4; ++nt)
            #pragma unroll
            for (int ks = 0; ks < 2; ++ks)
                kf[nt][ks] = *(const bf16x8s*)(Kbase + ((((kc >> 4) + nt) * 2 + ks) << 9) + ln * 8);
    }

    for (int it = 0; it < 32; ++it) {
        const int kc = kq * 2048 + it * 64;

        bf16x8s vf[4][2];
        #pragma unroll
        for (int dt = 0; dt < 4; ++dt)
            #pragma unroll
            for (int ks = 0; ks < 2; ++ks)
                vf[dt][ks] = *(const bf16x8s*)(Vbase + ((dt * 256 + (kc >> 5) + ks) << 9) + ln * 8);

        f32x4 st[2][4] = {};
        #pragma unroll
        for (int kt = 0; kt < 4; ++kt)
            #pragma unroll
            for (int mt = 0; mt < 2; ++mt) {
                st[mt][kt] = __builtin_amdgcn_mfma_f32_16x16x32_bf16(kf[kt][0], qf[mt][0], st[mt][kt], 0, 0, 0);
                st[mt][kt] = __builtin_amdgcn_mfma_f32_16x16x32_bf16(kf[kt][1], qf[mt][1], st[mt][kt], 0, 0, 0);
            }

        if (it + 1 < 32) {
            const int kn = kq * 2048 + (it + 1) * 64;
            #pragma unroll
            for (int nt = 0; nt < 4; ++nt)
                #pragma unroll
                for (int ks = 0; ks < 2; ++ks)
                    kf[nt][ks] = *(const bf16x8s*)(Kbase + ((((kn >> 4) + nt) * 2 + ks) << 9) + ln * 8);
        }

        unsigned pp[2][4][2];
        #pragma unroll
        for (int mt = 0; mt < 2; ++mt)
            #pragma unroll
            for (int kt = 0; kt < 4; ++kt) {
                const float p0 = fexp2(st[mt][kt][0]);
                const float p1 = fexp2(st[mt][kt][1]);
                const float p2 = fexp2(st[mt][kt][2]);
                const float p3 = fexp2(st[mt][kt][3]);
                pp[mt][kt][0] = pk2(p0, p1);
                pp[mt][kt][1] = pk2(p2, p3);
            }

        #pragma unroll
        for (int mt = 0; mt < 2; ++mt)
            #pragma unroll
            for (int ks = 0; ks < 2; ++ks) {
                const unsigned a0 = __shfl(pp[mt][2 * ks][0], srcLo);
                const unsigned b0 = __shfl(pp[mt][2 * ks + 1][0], srcLo);
                const unsigned a1 = __shfl(pp[mt][2 * ks][1], srcLo);
                const unsigned b1 = __shfl(pp[mt][2 * ks + 1][1], srcLo);
                const unsigned a2 = __shfl(pp[mt][2 * ks][0], srcHi);
                const unsigned b2 = __shfl(pp[mt][2 * ks + 1][0], srcHi);
                const unsigned a3 = __shfl(pp[mt][2 * ks][1], srcHi);
                const unsigned b3 = __shfl(pp[mt][2 * ks + 1][1], srcHi);
                uint4 pb;
                pb.x = ktHi ? b0 : a0;
                pb.y = ktHi ? b1 : a1;
                pb.z = ktHi ? b2 : a2;
                pb.w = ktHi ? b3 : a3;
                bf16x8s pbv = *reinterpret_cast<bf16x8s*>(&pb);
                #pragma unroll
                for (int dt = 0; dt < 4; ++dt)
                    o[mt][dt] = __builtin_amdgcn_mfma_f32_16x16x32_bf16(vf[dt][ks], pbv, o[mt][dt], 0, 0, 0);
                lsum[mt] = __builtin_amdgcn_mfma_f32_16x16x32_bf16(ones, pbv, lsum[mt], 0, 0, 0);
            }
    }

    // partial O store (unnormalized, O^T in regs: d = dt*16+quad*4+r, q = m16)
    float* Pq = Po + (size_t)kq * (2048 * 512);
    #pragma unroll
    for (int mt = 0; mt < 2; ++mt) {
        const int row = b * NQ + qt * 128 + w * 32 + mt * 16 + m16;
        #pragma unroll
        for (int dt = 0; dt < 4; ++dt)
            *(f32x4*)(Pq + (size_t)row * 512 + h * 64 + dt * 16 + quad * 4) = o[mt][dt];
    }
    // l partial accumulate (every C row holds the same value; use row 0)
    if (quad == 0) {
        const int n0 = qt * 128 + w * 32 + m16;
        atomicAdd(&Lg[(size_t)bh * NQ + n0],      lsum[0][0]);
        atomicAdd(&Lg[(size_t)bh * NQ + n0 + 16], lsum[1][0]);
    }
}

// ---------------------------------------------------------------------------
// Out-projection (barrier-free, no LDS): merges the 4 partial-O quarters,
// normalizes by 1/l, then A @ Wo + bias. 512 blocks.
// ---------------------------------------------------------------------------
__global__ __launch_bounds__(256) void gemm_out(
    const float* __restrict__ Po,   // [4][2048][512]
    const float* __restrict__ Lg,   // [B*H][512]
    const short* __restrict__ Wf,
    float* __restrict__ C, const float* __restrict__ bias)
{
    const int tm = (int)(blockIdx.x >> 3);
    const int tn = (int)(blockIdx.x & 7);
    const int t = threadIdx.x;
    const int w = t >> 6, ln = t & 63;
    const int m16 = ln & 15, quad = ln >> 4;
    const int wm = w >> 1, wn = w & 1;

    const int row = tm * 32 + wm * 16 + m16;     // 0..2047
    const int b   = row >> 9, n = row & 511;

    // per-lane reciprocal softmax sums for all 8 heads
    float linv[8];
    #pragma unroll
    for (int hh = 0; hh < 8; ++hh)
        linv[hh] = 1.0f / Lg[(size_t)(b * NH + hh) * NQ + n];

    const float* Ap = Po + (size_t)row * 512 + quad * 8;

    f32x4 acc[2] = {};

    for (int k0 = 0; k0 < 512; k0 += 64) {
        const float sc = linv[k0 >> 6];
        #pragma unroll
        for (int ks = 0; ks < 2; ++ks) {
            const float* p0 = Ap + k0 + ks * 32;
            float4 a0 = *(const float4*)(p0);
            float4 a1 = *(const float4*)(p0 + 4);
            #pragma unroll
            for (int qq = 1; qq < 4; ++qq) {
                float4 c0 = *(const float4*)(p0 + (size_t)qq * (2048 * 512));
                float4 c1 = *(const float4*)(p0 + (size_t)qq * (2048 * 512) + 4);
                a0.x += c0.x; a0.y += c0.y; a0.z += c0.z; a0.w += c0.w;
                a1.x += c1.x; a1.y += c1.y; a1.z += c1.z; a1.w += c1.w;
            }
            uint4 wa = { pk2(a0.x * sc, a0.y * sc), pk2(a0.z * sc, a0.w * sc),
                         pk2(a1.x * sc, a1.y * sc), pk2(a1.z * sc, a1.w * sc) };
            bf16x8s af = *reinterpret_cast<bf16x8s*>(&wa);
            #pragma unroll
            for (int nt = 0; nt < 2; ++nt) {
                bf16x8s bf = *(const bf16x8s*)(Wf +
                    ((size_t)((tn * 4 + wn * 2 + nt) * 16 + (k0 >> 5) + ks) * 64 + ln) * 8);
                acc[nt] = __builtin_amdgcn_mfma_f32_16x16x32_bf16(af, bf, acc[nt], 0, 0, 0);
            }
        }
    }

    const int row0 = tm * 32 + wm * 16 + quad * 4;
    const int col0 = tn * 64 + wn * 32;
    #pragma unroll
    for (int nt = 0; nt < 2; ++nt) {
        const int col = col0 + nt * 16 + m16;
        const float bb = bias[col];
        #pragma unroll
        for (int r = 0; r < 4; ++r)
            C[(size_t)(row0 + r) * 512 + col] = acc[nt][r] + bb;
    }
}

// ---------------------------------------------------------------------------
extern "C" void kernel_launch(void* const* d_in, const int* in_sizes, int n_in,
                              void* d_out, int out_size, void* d_ws, size_t ws_size,
                              hipStream_t stream) {
    (void)in_sizes; (void)n_in; (void)out_size; (void)ws_size;

    const float* x   = (const float*)d_in[0];   // [4, 512, 512]
    const float* ctx = (const float*)d_in[1];   // [4, 8192, 256]
    const float* Wq  = (const float*)d_in[2];   // [512, 512]
    const float* Wkv = (const float*)d_in[3];   // [256, 1024]
    const float* Wo  = (const float*)d_in[4];   // [512, 512]
    const float* bo  = (const float*)d_in[5];   // [512]
    float* out = (float*)d_out;                 // [4, 512, 512]

    float* ws   = (float*)d_ws;
    float* q    = ws;                                        // 4 MB fp32
    float* Po   = q  + (size_t)2048 * 512;                   // 16 MB fp32 [4][2048][512]
    float* Lg   = Po + (size_t)4 * 2048 * 512;               // 64 KB fp32
    short* Kf   = (short*)(Lg + (size_t)32 * 512);           // 33.5 MB bf16 (fragment order)
    short* Vf   = Kf + (size_t)NB * NH * NM * DH;            // 33.5 MB bf16 (fragment order)
    short* Wqf  = Vf + (size_t)NB * NH * NM * DH;            // 512 KB
    short* Wof  = Wqf + (size_t)512 * 512;                   // 512 KB
    short* Wkvf = Wof + (size_t)512 * 512;                   // 512 KB

    // zero the atomic softmax-sum buffer
    hipMemsetAsync(Lg, 0, (size_t)32 * 512 * sizeof(float), stream);

    // weights -> bf16 fragment order
    prep_weights<<<dim3(384), dim3(256), 0, stream>>>(Wq, Wo, Wkv, Wqf, Wof, Wkvf);

    // q = x@Wq (512 blocks) + kv = ctx@Wkv (2048 blocks), barrier-free
    gemm_kvq<<<dim3(2560), dim3(256), 0, stream>>>(x, Wqf, q, ctx, Wkvf, Kf, Vf);

    // flash attention: 32 bh x 4 qt x 4 kq = 512 blocks, LDS/barrier-free
    attn_mfma<<<dim3(512), dim3(256), 0, stream>>>(q, Kf, Vf, Po, Lg);

    // out = merge(Po)/l @ Wo + bo (512 blocks)
    gemm_out<<<dim3(512), dim3(256), 0, stream>>>(Po, Lg, Wof, out, bo);
}

// Round 10
// 207.816 us; speedup vs baseline: 1.2590x; 1.2590x over previous
//
#include <hip/hip_runtime.h>
#include <hip/hip_bf16.h>
#include <cstdint>

#define NB 4
#define NQ 512
#define NM 8192
#define NH 8
#define DH 64

typedef short bf16x8s __attribute__((ext_vector_type(8)));
typedef float f32x4  __attribute__((ext_vector_type(4)));

// fast fp32->bf16 (round-half-up)
static __device__ __forceinline__ short f2bs(float f) {
    unsigned u = __builtin_bit_cast(unsigned, f);
    return (short)(unsigned short)((u + 0x8000u) >> 16);
}
// packed pair via v_perm_b32: lo16 = bf16(a), hi16 = bf16(b)
static __device__ __forceinline__ unsigned pk2(float a, float b) {
    unsigned au = __builtin_bit_cast(unsigned, a) + 0x8000u;
    unsigned bu = __builtin_bit_cast(unsigned, b) + 0x8000u;
    return __builtin_amdgcn_perm(bu, au, 0x07060302u);
}

#if __has_builtin(__builtin_amdgcn_exp2f)
static __device__ __forceinline__ float fexp2(float x) { return __builtin_amdgcn_exp2f(x); }
#else
static __device__ __forceinline__ float fexp2(float x) { return exp2f(x); }
#endif

// ---------------------------------------------------------------------------
// Weight prep: Wq/Wo [512,512], Wkv [256,1024] (fp32 [k][n]) -> bf16 MFMA
// B-fragment order: Wf[(n0*KS + ks)*64 + lane][j] = W[ks*32+quad*8+j][n0*16+m16]
// ---------------------------------------------------------------------------
__global__ __launch_bounds__(256) void prep_weights(
    const float* __restrict__ Wq, const float* __restrict__ Wo,
    const float* __restrict__ Wkv,
    short* __restrict__ Wqf, short* __restrict__ Wof, short* __restrict__ Wkvf)
{
    const int t = threadIdx.x;
    const int w = t >> 6, ln = t & 63;
    const int m16 = ln & 15, quad = ln >> 4;
    int f = blockIdx.x * 4 + w;           // 0..1535
    const float* src; short* dst; int N, KS, n0, ks;
    if (f < 512)       { src = Wq;  dst = Wqf;  N = 512;  KS = 16; n0 = f >> 4; ks = f & 15; }
    else if (f < 1024) { f -= 512;  src = Wo;  dst = Wof;  N = 512;  KS = 16; n0 = f >> 4; ks = f & 15; }
    else               { f -= 1024; src = Wkv; dst = Wkvf; N = 1024; KS = 8;  n0 = f >> 3; ks = f & 7; }
    const float* sp = src + (size_t)(ks * 32 + quad * 8) * N + n0 * 16 + m16;
    float v[8];
    #pragma unroll
    for (int j = 0; j < 8; ++j) v[j] = sp[(size_t)j * N];
    uint4 pkv = { pk2(v[0],v[1]), pk2(v[2],v[3]), pk2(v[4],v[5]), pk2(v[6],v[7]) };
    *(uint4*)(dst + ((size_t)(n0 * KS + ks) * 64 + ln) * 8) = pkv;
}

// ---------------------------------------------------------------------------
// Projection GEMM body (round-8 proven): C = A[2048,512] @ W[512,512] (+bias).
// 32x64 tile, BK=64; A via LDS staging, B-frags direct from frag-order
// weights. 512 blocks.
// ---------------------------------------------------------------------------
__device__ __forceinline__ void proj32_body(
    const float* __restrict__ A, const short* __restrict__ Wf,
    float* __restrict__ C, const float* __restrict__ bias,
    int tm, int tn, char* smemraw)
{
    short* As = (short*)smemraw;        // [32][72]

    const int t = threadIdx.x;
    const int w = t >> 6, ln = t & 63;
    const int m16 = ln & 15, quad = ln >> 4;
    const int wm = w >> 1, wn = w & 1;

    const int ar = t >> 3, ac = (t & 7) << 3;      // A: 32 rows x 64 k

    const float* Ap = A + (size_t)(tm * 32 + ar) * 512 + ac;

    f32x4 acc[2] = {};

    for (int k0 = 0; k0 < 512; k0 += 64) {
        float4 a0 = *(const float4*)(Ap + k0);
        float4 a1 = *(const float4*)(Ap + k0 + 4);
        bf16x8s bfr[2][2];
        #pragma unroll
        for (int ks = 0; ks < 2; ++ks)
            #pragma unroll
            for (int nt = 0; nt < 2; ++nt)
                bfr[ks][nt] = *(const bf16x8s*)(Wf +
                    ((size_t)((tn * 4 + wn * 2 + nt) * 16 + (k0 >> 5) + ks) * 64 + ln) * 8);

        __syncthreads();
        {
            uint4 wa = { pk2(a0.x,a0.y), pk2(a0.z,a0.w), pk2(a1.x,a1.y), pk2(a1.z,a1.w) };
            *(uint4*)&As[ar * 72 + ac] = wa;
        }
        __syncthreads();

        #pragma unroll
        for (int ks = 0; ks < 2; ++ks) {
            bf16x8s af = *(const bf16x8s*)&As[(wm * 16 + m16) * 72 + ks * 32 + quad * 8];
            #pragma unroll
            for (int nt = 0; nt < 2; ++nt)
                acc[nt] = __builtin_amdgcn_mfma_f32_16x16x32_bf16(af, bfr[ks][nt], acc[nt], 0, 0, 0);
        }
    }

    const int row0 = tm * 32 + wm * 16 + quad * 4;
    const int col0 = tn * 64 + wn * 32;
    #pragma unroll
    for (int nt = 0; nt < 2; ++nt) {
        const int col = col0 + nt * 16 + m16;
        const float bb = bias ? bias[col] : 0.f;
        #pragma unroll
        for (int r = 0; r < 4; ++r)
            C[(size_t)(row0 + r) * 512 + col] = acc[nt][r] + bb;
    }
}

// ---------------------------------------------------------------------------
// kv GEMM body (round-8 proven): 128x128 tile, BK=32, K=256; A via LDS,
// B-frags direct from frag-order Wkv. Fragment-order K/V epilogue.
// tm = bid&255 keeps the 8 n-tiles of an m-tile on one XCD.
// ---------------------------------------------------------------------------
__device__ __forceinline__ void kv_body(
    const float* __restrict__ A, const short* __restrict__ Wkvf,
    short* __restrict__ Kf, short* __restrict__ Vf,
    int bid, char* smemraw)
{
    short* As = (short*)smemraw;        // [128][40]

    const int t  = threadIdx.x;
    const int tm = bid & 255, tn = bid >> 8;
    const int w  = t >> 6, ln = t & 63;
    const int m16 = ln & 15, quad = ln >> 4;
    const int wm = w & 1, wn = w >> 1;

    const int ar = t >> 3;
    const int ac = (t & 7) << 2;

    const float* Abase = A + (size_t)(tm * 128 + ar) * 256 + ac;

    f32x4 acc[4][4] = {};

    for (int k0 = 0; k0 < 256; k0 += 32) {
        float4 av[4];
        #pragma unroll
        for (int p = 0; p < 4; ++p)
            av[p] = *(const float4*)(Abase + (size_t)p * 32 * 256 + k0);
        bf16x8s bfr[4];
        #pragma unroll
        for (int j = 0; j < 4; ++j)
            bfr[j] = *(const bf16x8s*)(Wkvf +
                ((size_t)((tn * 8 + wn * 4 + j) * 8 + (k0 >> 5)) * 64 + ln) * 8);

        __syncthreads();
        #pragma unroll
        for (int p = 0; p < 4; ++p) {
            uint2 wv = { pk2(av[p].x, av[p].y), pk2(av[p].z, av[p].w) };
            *(uint2*)&As[(p * 32 + ar) * 40 + ac] = wv;
        }
        __syncthreads();

        bf16x8s af[4];
        #pragma unroll
        for (int i = 0; i < 4; ++i)
            af[i] = *(const bf16x8s*)&As[(wm * 64 + i * 16 + m16) * 40 + quad * 8];
        #pragma unroll
        for (int i = 0; i < 4; ++i)
            #pragma unroll
            for (int j = 0; j < 4; ++j)
                acc[i][j] = __builtin_amdgcn_mfma_f32_16x16x32_bf16(af[i], bfr[j], acc[i][j], 0, 0, 0);
    }

    const int col0 = tn * 128 + wn * 64;
    const int row0 = tm * 128 + wm * 64;
    const int b    = row0 >> 13;
    const int mr0  = row0 & (NM - 1);

    if (col0 < 512) {
        const int h = col0 >> 6;
        short* Kp = Kf + (size_t)(b * NH + h) * (NM * DH);
        #pragma unroll
        for (int i = 0; i < 4; ++i)
            #pragma unroll
            for (int j = 0; j < 4; ++j) {
                const int d = j * 16 + m16;
                #pragma unroll
                for (int r = 0; r < 4; ++r) {
                    const int key = mr0 + i * 16 + quad * 4 + r;
                    const int idx = ((key >> 4) * 2 + (d >> 5)) * 512
                                  + (((d >> 3) & 3) * 16 + (key & 15)) * 8 + (d & 7);
                    Kp[idx] = f2bs(acc[i][j][r]);
                }
            }
    } else {
        const int h = (col0 - 512) >> 6;
        short* Vp = Vf + (size_t)(b * NH + h) * (NM * DH);
        #pragma unroll
        for (int i = 0; i < 4; ++i)
            #pragma unroll
            for (int j = 0; j < 4; ++j) {
                const int key0 = mr0 + i * 16 + quad * 4;
                const int idx = (j * 256 + (key0 >> 5)) * 512
                              + ((((key0 >> 3) & 3) * 16 + m16) * 8) + (key0 & 7);
                uint2 pk;
                pk.x = pk2(acc[i][j][0], acc[i][j][1]);
                pk.y = pk2(acc[i][j][2], acc[i][j][3]);
                *(uint2*)(Vp + idx) = pk;
            }
    }
}

// ---------------------------------------------------------------------------
// Uber kernel: blocks 0..511 do q = x@Wq (proj32), blocks 512..2559 do kv.
// ---------------------------------------------------------------------------
__global__ __launch_bounds__(256) void gemm_kvq(
    const float* __restrict__ x,   const short* __restrict__ Wqf, float* __restrict__ q,
    const float* __restrict__ ctx, const short* __restrict__ Wkvf,
    short* __restrict__ Kf, short* __restrict__ Vf)
{
    __shared__ __align__(16) char smem[10240];
    if (blockIdx.x < 512)
        proj32_body(x, Wqf, q, nullptr, (int)(blockIdx.x >> 3), (int)(blockIdx.x & 7), smem);
    else
        kv_body(ctx, Wkvf, Kf, Vf, (int)(blockIdx.x - 512), smem);
}

// out-projection: 512 blocks
__global__ __launch_bounds__(256) void gemm_proj32(
    const float* __restrict__ A, const short* __restrict__ Wf,
    float* __restrict__ C, const float* __restrict__ bias)
{
    __shared__ __align__(16) char smem[32 * 72 * 2];
    proj32_body(A, Wf, C, bias, (int)(blockIdx.x >> 3), (int)(blockIdx.x & 7), smem);
}

// ---------------------------------------------------------------------------
// MFMA flash attention, 64-row q-tiles (halves L2 K/V traffic vs 32-row).
// Block = (bh, 64 q-rows), 256 blocks = 1/CU. Wave w owns 64-key chunks
// it*256+w*64 (wave-private l via ones-MFMA); K-loop is barrier-free.
// S^T formulation, exp2-domain no-max softmax, P^T via quad shuffles.
// Epilogue: 2-phase LDS merge (waves 0/2 write, waves 1/3 add), then
// normalize + store.
// ---------------------------------------------------------------------------
__global__ __launch_bounds__(256, 1) void attn_mfma(
    const float* __restrict__ Q,    // [2048, 512] fp32
    const short* __restrict__ Kfr,  // fragment-order K
    const short* __restrict__ Vfr,  // fragment-order V
    float* __restrict__ Og)         // [2048, 512] fp32
{
    __shared__ __align__(16) float Ob[2][64 * 66];   // 33.8 KB
    __shared__ float lbuf[4 * 64];

    const int bid = blockIdx.x;
    const int xcd = bid & 7, g = bid >> 3;
    const int bh  = xcd * 4 + (g & 3);     // 8 qt-blocks of one bh share bid%8
    const int qt  = g >> 2;                // 0..7 (64-row tiles)
    const int b   = bh >> 3, h = bh & 7;
    const int t   = threadIdx.x;
    const int w   = t >> 6, ln = t & 63;
    const int m16 = ln & 15, quad = ln >> 4;

    const short* Kbase = Kfr + (size_t)bh * (NM * DH);
    const short* Vbase = Vfr + (size_t)bh * (NM * DH);

    // Q scaled by (1/8) * log2(e)  -> scores in log2 domain
    const float qsc = 0.125f * 1.44269504f;
    bf16x8s qf[4][2];
    #pragma unroll
    for (int mt = 0; mt < 4; ++mt) {
        const float* qrow = Q + ((size_t)(b * NQ + qt * 64 + mt * 16 + m16)) * 512 + h * 64;
        #pragma unroll
        for (int ks = 0; ks < 2; ++ks) {
            float4 x0 = *(const float4*)(qrow + ks * 32 + quad * 8);
            float4 x1 = *(const float4*)(qrow + ks * 32 + quad * 8 + 4);
            uint4 pkv = { pk2(x0.x * qsc, x0.y * qsc), pk2(x0.z * qsc, x0.w * qsc),
                          pk2(x1.x * qsc, x1.y * qsc), pk2(x1.z * qsc, x1.w * qsc) };
            qf[mt][ks] = *reinterpret_cast<bf16x8s*>(&pkv);
        }
    }

    bf16x8s ones;
    #pragma unroll
    for (int j = 0; j < 8; ++j) ones[j] = (short)0x3F80;

    f32x4 o[4][4] = {};
    f32x4 lsum[4] = {};

    const int srcLo = (((quad << 1) & 3) << 4) + m16;
    const int srcHi = ((((quad << 1) + 1) & 3) << 4) + m16;
    const bool ktHi = quad >= 2;

    bf16x8s kf[4][2];
    {
        const int kc = w * 64;
        #pragma unroll
        for (int nt = 0; nt < 4; ++nt)
            #pragma unroll
            for (int ks = 0; ks < 2; ++ks)
                kf[nt][ks] = *(const bf16x8s*)(Kbase + ((((kc >> 4) + nt) * 2 + ks) << 9) + ln * 8);
    }

    for (int it = 0; it < 32; ++it) {
        const int kc = it * 256 + w * 64;

        bf16x8s vf[4][2];
        #pragma unroll
        for (int dt = 0; dt < 4; ++dt)
            #pragma unroll
            for (int ks = 0; ks < 2; ++ks)
                vf[dt][ks] = *(const bf16x8s*)(Vbase + ((dt * 256 + (kc >> 5) + ks) << 9) + ln * 8);

        f32x4 st[4][4] = {};
        #pragma unroll
        for (int kt = 0; kt < 4; ++kt)
            #pragma unroll
            for (int mt = 0; mt < 4; ++mt) {
                st[mt][kt] = __builtin_amdgcn_mfma_f32_16x16x32_bf16(kf[kt][0], qf[mt][0], st[mt][kt], 0, 0, 0);
                st[mt][kt] = __builtin_amdgcn_mfma_f32_16x16x32_bf16(kf[kt][1], qf[mt][1], st[mt][kt], 0, 0, 0);
            }

        if (it + 1 < 32) {
            const int kn = (it + 1) * 256 + w * 64;
            #pragma unroll
            for (int nt = 0; nt < 4; ++nt)
                #pragma unroll
                for (int ks = 0; ks < 2; ++ks)
                    kf[nt][ks] = *(const bf16x8s*)(Kbase + ((((kn >> 4) + nt) * 2 + ks) << 9) + ln * 8);
        }

        // p = 2^s, packed to bf16 pairs
        unsigned pp[4][4][2];
        #pragma unroll
        for (int mt = 0; mt < 4; ++mt)
            #pragma unroll
            for (int kt = 0; kt < 4; ++kt) {
                const float p0 = fexp2(st[mt][kt][0]);
                const float p1 = fexp2(st[mt][kt][1]);
                const float p2 = fexp2(st[mt][kt][2]);
                const float p3 = fexp2(st[mt][kt][3]);
                pp[mt][kt][0] = pk2(p0, p1);
                pp[mt][kt][1] = pk2(p2, p3);
            }

        // P^T -> B-frag via quad permutation; O^T += V^T @ P^T; l += 1 @ P^T
        #pragma unroll
        for (int mt = 0; mt < 4; ++mt)
            #pragma unroll
            for (int ks = 0; ks < 2; ++ks) {
                const unsigned a0 = __shfl(pp[mt][2 * ks][0], srcLo);
                const unsigned b0 = __shfl(pp[mt][2 * ks + 1][0], srcLo);
                const unsigned a1 = __shfl(pp[mt][2 * ks][1], srcLo);
                const unsigned b1 = __shfl(pp[mt][2 * ks + 1][1], srcLo);
                const unsigned a2 = __shfl(pp[mt][2 * ks][0], srcHi);
                const unsigned b2 = __shfl(pp[mt][2 * ks + 1][0], srcHi);
                const unsigned a3 = __shfl(pp[mt][2 * ks][1], srcHi);
                const unsigned b3 = __shfl(pp[mt][2 * ks + 1][1], srcHi);
                uint4 pb;
                pb.x = ktHi ? b0 : a0;
                pb.y = ktHi ? b1 : a1;
                pb.z = ktHi ? b2 : a2;
                pb.w = ktHi ? b3 : a3;
                bf16x8s pbv = *reinterpret_cast<bf16x8s*>(&pb);
                #pragma unroll
                for (int dt = 0; dt < 4; ++dt)
                    o[mt][dt] = __builtin_amdgcn_mfma_f32_16x16x32_bf16(vf[dt][ks], pbv, o[mt][dt], 0, 0, 0);
                lsum[mt] = __builtin_amdgcn_mfma_f32_16x16x32_bf16(ones, pbv, lsum[mt], 0, 0, 0);
            }
    }

    // ---- epilogue: l partials + 2-phase O merge ----
    if (quad == 0) {
        #pragma unroll
        for (int mt = 0; mt < 4; ++mt)
            lbuf[w * 64 + mt * 16 + m16] = lsum[mt][0];
    }
    // Phase A: waves 0 and 2 write their O^T into the two buffers
    if ((w & 1) == 0) {
        float* dst = Ob[w >> 1];
        #pragma unroll
        for (int mt = 0; mt < 4; ++mt)
            #pragma unroll
            for (int dt = 0; dt < 4; ++dt)
                *(f32x4*)&dst[(mt * 16 + m16) * 66 + dt * 16 + quad * 4] = o[mt][dt];
    }
    __syncthreads();
    // Phase B: waves 1 and 3 add into the buffers
    if ((w & 1) == 1) {
        float* dst = Ob[w >> 1];
        #pragma unroll
        for (int mt = 0; mt < 4; ++mt)
            #pragma unroll
            for (int dt = 0; dt < 4; ++dt) {
                float* p = &dst[(mt * 16 + m16) * 66 + dt * 16 + quad * 4];
                f32x4 cur = *(f32x4*)p;
                cur += o[mt][dt];
                *(f32x4*)p = cur;
            }
    }
    __syncthreads();
    // Phase C: combine the two buffers, normalize, store
    {
        const int row = t >> 2;             // 0..63
        const int d0  = (t & 3) << 4;       // 0,16,32,48
        const float l = lbuf[row] + lbuf[64 + row] + lbuf[128 + row] + lbuf[192 + row];
        const float inv = 1.0f / l;
        float* op = Og + ((size_t)(b * NQ + qt * 64 + row)) * 512 + h * 64 + d0;
        #pragma unroll
        for (int j = 0; j < 4; ++j) {
            const int c = row * 66 + d0 + j * 4;
            float4 r;
            r.x = (Ob[0][c + 0] + Ob[1][c + 0]) * inv;
            r.y = (Ob[0][c + 1] + Ob[1][c + 1]) * inv;
            r.z = (Ob[0][c + 2] + Ob[1][c + 2]) * inv;
            r.w = (Ob[0][c + 3] + Ob[1][c + 3]) * inv;
            *(float4*)(op + j * 4) = r;
        }
    }
}

// ---------------------------------------------------------------------------
extern "C" void kernel_launch(void* const* d_in, const int* in_sizes, int n_in,
                              void* d_out, int out_size, void* d_ws, size_t ws_size,
                              hipStream_t stream) {
    (void)in_sizes; (void)n_in; (void)out_size; (void)ws_size;

    const float* x   = (const float*)d_in[0];   // [4, 512, 512]
    const float* ctx = (const float*)d_in[1];   // [4, 8192, 256]
    const float* Wq  = (const float*)d_in[2];   // [512, 512]
    const float* Wkv = (const float*)d_in[3];   // [256, 1024]
    const float* Wo  = (const float*)d_in[4];   // [512, 512]
    const float* bo  = (const float*)d_in[5];   // [512]
    float* out = (float*)d_out;                 // [4, 512, 512]

    float* ws    = (float*)d_ws;
    float* q     = ws;                                       // 4 MB fp32
    float* attno = q + (size_t)2048 * 512;                   // 4 MB fp32
    short* Kf    = (short*)(attno + (size_t)2048 * 512);     // 33.5 MB bf16 (fragment order)
    short* Vf    = Kf + (size_t)NB * NH * NM * DH;           // 33.5 MB bf16 (fragment order)
    short* Wqf   = Vf + (size_t)NB * NH * NM * DH;           // 512 KB
    short* Wof   = Wqf + (size_t)512 * 512;                  // 512 KB
    short* Wkvf  = Wof + (size_t)512 * 512;                  // 512 KB

    // weights -> bf16 fragment order
    prep_weights<<<dim3(384), dim3(256), 0, stream>>>(Wq, Wo, Wkv, Wqf, Wof, Wkvf);

    // q = x@Wq (512 blocks) + kv = ctx@Wkv (2048 blocks) in one launch
    gemm_kvq<<<dim3(2560), dim3(256), 0, stream>>>(x, Wqf, q, ctx, Wkvf, Kf, Vf);

    // flash attention: 32 bh x 8 q-tiles = 256 blocks (1/CU)
    attn_mfma<<<dim3(256), dim3(256), 0, stream>>>(q, Kf, Vf, attno);

    // out = attno @ Wo + bo (512 blocks)
    gemm_proj32<<<dim3(512), dim3(256), 0, stream>>>(attno, Wof, out, bo);
}

// Round 11
// 189.576 us; speedup vs baseline: 1.3801x; 1.0962x over previous
//
#include <hip/hip_runtime.h>
#include <hip/hip_bf16.h>
#include <cstdint>

#define NB 4
#define NQ 512
#define NM 8192
#define NH 8
#define DH 64

typedef short bf16x8s __attribute__((ext_vector_type(8)));
typedef float f32x4  __attribute__((ext_vector_type(4)));

// fast fp32->bf16 (round-half-up)
static __device__ __forceinline__ short f2bs(float f) {
    unsigned u = __builtin_bit_cast(unsigned, f);
    return (short)(unsigned short)((u + 0x8000u) >> 16);
}
// packed pair via v_perm_b32: lo16 = bf16(a), hi16 = bf16(b)
static __device__ __forceinline__ unsigned pk2(float a, float b) {
    unsigned au = __builtin_bit_cast(unsigned, a) + 0x8000u;
    unsigned bu = __builtin_bit_cast(unsigned, b) + 0x8000u;
    return __builtin_amdgcn_perm(bu, au, 0x07060302u);
}

#if __has_builtin(__builtin_amdgcn_exp2f)
static __device__ __forceinline__ float fexp2(float x) { return __builtin_amdgcn_exp2f(x); }
#else
static __device__ __forceinline__ float fexp2(float x) { return exp2f(x); }
#endif

// ---------------------------------------------------------------------------
// Weight prep: Wq/Wo [512,512], Wkv [256,1024] (fp32 [k][n]) -> bf16 MFMA
// B-fragment order: Wf[(n0*KS + ks)*64 + lane][j] = W[ks*32+quad*8+j][n0*16+m16]
// ---------------------------------------------------------------------------
__global__ __launch_bounds__(256) void prep_weights(
    const float* __restrict__ Wq, const float* __restrict__ Wo,
    const float* __restrict__ Wkv,
    short* __restrict__ Wqf, short* __restrict__ Wof, short* __restrict__ Wkvf)
{
    const int t = threadIdx.x;
    const int w = t >> 6, ln = t & 63;
    const int m16 = ln & 15, quad = ln >> 4;
    int f = blockIdx.x * 4 + w;           // 0..1535
    const float* src; short* dst; int N, KS, n0, ks;
    if (f < 512)       { src = Wq;  dst = Wqf;  N = 512;  KS = 16; n0 = f >> 4; ks = f & 15; }
    else if (f < 1024) { f -= 512;  src = Wo;  dst = Wof;  N = 512;  KS = 16; n0 = f >> 4; ks = f & 15; }
    else               { f -= 1024; src = Wkv; dst = Wkvf; N = 1024; KS = 8;  n0 = f >> 3; ks = f & 7; }
    const float* sp = src + (size_t)(ks * 32 + quad * 8) * N + n0 * 16 + m16;
    float v[8];
    #pragma unroll
    for (int j = 0; j < 8; ++j) v[j] = sp[(size_t)j * N];
    uint4 pkv = { pk2(v[0],v[1]), pk2(v[2],v[3]), pk2(v[4],v[5]), pk2(v[6],v[7]) };
    *(uint4*)(dst + ((size_t)(n0 * KS + ks) * 64 + ln) * 8) = pkv;
}

// ---------------------------------------------------------------------------
// Projection GEMM body: C = A[2048,512] @ W[512,512] (+bias).
// 32x64 tile, BK=64; A via LDS staging, B-frags direct from frag-order
// weights. 512 blocks.
// ---------------------------------------------------------------------------
__device__ __forceinline__ void proj32_body(
    const float* __restrict__ A, const short* __restrict__ Wf,
    float* __restrict__ C, const float* __restrict__ bias,
    int tm, int tn, char* smemraw)
{
    short* As = (short*)smemraw;        // [32][72]

    const int t = threadIdx.x;
    const int w = t >> 6, ln = t & 63;
    const int m16 = ln & 15, quad = ln >> 4;
    const int wm = w >> 1, wn = w & 1;

    const int ar = t >> 3, ac = (t & 7) << 3;      // A: 32 rows x 64 k

    const float* Ap = A + (size_t)(tm * 32 + ar) * 512 + ac;

    f32x4 acc[2] = {};

    for (int k0 = 0; k0 < 512; k0 += 64) {
        float4 a0 = *(const float4*)(Ap + k0);
        float4 a1 = *(const float4*)(Ap + k0 + 4);
        bf16x8s bfr[2][2];
        #pragma unroll
        for (int ks = 0; ks < 2; ++ks)
            #pragma unroll
            for (int nt = 0; nt < 2; ++nt)
                bfr[ks][nt] = *(const bf16x8s*)(Wf +
                    ((size_t)((tn * 4 + wn * 2 + nt) * 16 + (k0 >> 5) + ks) * 64 + ln) * 8);

        __syncthreads();
        {
            uint4 wa = { pk2(a0.x,a0.y), pk2(a0.z,a0.w), pk2(a1.x,a1.y), pk2(a1.z,a1.w) };
            *(uint4*)&As[ar * 72 + ac] = wa;
        }
        __syncthreads();

        #pragma unroll
        for (int ks = 0; ks < 2; ++ks) {
            bf16x8s af = *(const bf16x8s*)&As[(wm * 16 + m16) * 72 + ks * 32 + quad * 8];
            #pragma unroll
            for (int nt = 0; nt < 2; ++nt)
                acc[nt] = __builtin_amdgcn_mfma_f32_16x16x32_bf16(af, bfr[ks][nt], acc[nt], 0, 0, 0);
        }
    }

    const int row0 = tm * 32 + wm * 16 + quad * 4;
    const int col0 = tn * 64 + wn * 32;
    #pragma unroll
    for (int nt = 0; nt < 2; ++nt) {
        const int col = col0 + nt * 16 + m16;
        const float bb = bias ? bias[col] : 0.f;
        #pragma unroll
        for (int r = 0; r < 4; ++r)
            C[(size_t)(row0 + r) * 512 + col] = acc[nt][r] + bb;
    }
}

// ---------------------------------------------------------------------------
// kv GEMM body: 128x128 tile, BK=32, K=256; A via LDS, B-frags direct from
// frag-order Wkv. Fragment-order K/V epilogue. tm = bid&255 keeps the 8
// n-tiles of an m-tile on one XCD.
// ---------------------------------------------------------------------------
__device__ __forceinline__ void kv_body(
    const float* __restrict__ A, const short* __restrict__ Wkvf,
    short* __restrict__ Kf, short* __restrict__ Vf,
    int bid, char* smemraw)
{
    short* As = (short*)smemraw;        // [128][40]

    const int t  = threadIdx.x;
    const int tm = bid & 255, tn = bid >> 8;
    const int w  = t >> 6, ln = t & 63;
    const int m16 = ln & 15, quad = ln >> 4;
    const int wm = w & 1, wn = w >> 1;

    const int ar = t >> 3;
    const int ac = (t & 7) << 2;

    const float* Abase = A + (size_t)(tm * 128 + ar) * 256 + ac;

    f32x4 acc[4][4] = {};

    for (int k0 = 0; k0 < 256; k0 += 32) {
        float4 av[4];
        #pragma unroll
        for (int p = 0; p < 4; ++p)
            av[p] = *(const float4*)(Abase + (size_t)p * 32 * 256 + k0);
        bf16x8s bfr[4];
        #pragma unroll
        for (int j = 0; j < 4; ++j)
            bfr[j] = *(const bf16x8s*)(Wkvf +
                ((size_t)((tn * 8 + wn * 4 + j) * 8 + (k0 >> 5)) * 64 + ln) * 8);

        __syncthreads();
        #pragma unroll
        for (int p = 0; p < 4; ++p) {
            uint2 wv = { pk2(av[p].x, av[p].y), pk2(av[p].z, av[p].w) };
            *(uint2*)&As[(p * 32 + ar) * 40 + ac] = wv;
        }
        __syncthreads();

        bf16x8s af[4];
        #pragma unroll
        for (int i = 0; i < 4; ++i)
            af[i] = *(const bf16x8s*)&As[(wm * 64 + i * 16 + m16) * 40 + quad * 8];
        #pragma unroll
        for (int i = 0; i < 4; ++i)
            #pragma unroll
            for (int j = 0; j < 4; ++j)
                acc[i][j] = __builtin_amdgcn_mfma_f32_16x16x32_bf16(af[i], bfr[j], acc[i][j], 0, 0, 0);
    }

    const int col0 = tn * 128 + wn * 64;
    const int row0 = tm * 128 + wm * 64;
    const int b    = row0 >> 13;
    const int mr0  = row0 & (NM - 1);

    if (col0 < 512) {
        const int h = col0 >> 6;
        short* Kp = Kf + (size_t)(b * NH + h) * (NM * DH);
        #pragma unroll
        for (int i = 0; i < 4; ++i)
            #pragma unroll
            for (int j = 0; j < 4; ++j) {
                const int d = j * 16 + m16;
                #pragma unroll
                for (int r = 0; r < 4; ++r) {
                    const int key = mr0 + i * 16 + quad * 4 + r;
                    const int idx = ((key >> 4) * 2 + (d >> 5)) * 512
                                  + (((d >> 3) & 3) * 16 + (key & 15)) * 8 + (d & 7);
                    Kp[idx] = f2bs(acc[i][j][r]);
                }
            }
    } else {
        const int h = (col0 - 512) >> 6;
        short* Vp = Vf + (size_t)(b * NH + h) * (NM * DH);
        #pragma unroll
        for (int i = 0; i < 4; ++i)
            #pragma unroll
            for (int j = 0; j < 4; ++j) {
                const int key0 = mr0 + i * 16 + quad * 4;
                const int idx = (j * 256 + (key0 >> 5)) * 512
                              + ((((key0 >> 3) & 3) * 16 + m16) * 8) + (key0 & 7);
                uint2 pk;
                pk.x = pk2(acc[i][j][0], acc[i][j][1]);
                pk.y = pk2(acc[i][j][2], acc[i][j][3]);
                *(uint2*)(Vp + idx) = pk;
            }
    }
}

// ---------------------------------------------------------------------------
// Uber kernel: blocks 0..511 do q = x@Wq (proj32), blocks 512..2559 do kv.
// ---------------------------------------------------------------------------
__global__ __launch_bounds__(256) void gemm_kvq(
    const float* __restrict__ x,   const short* __restrict__ Wqf, float* __restrict__ q,
    const float* __restrict__ ctx, const short* __restrict__ Wkvf,
    short* __restrict__ Kf, short* __restrict__ Vf)
{
    __shared__ __align__(16) char smem[10240];
    if (blockIdx.x < 512)
        proj32_body(x, Wqf, q, nullptr, (int)(blockIdx.x >> 3), (int)(blockIdx.x & 7), smem);
    else
        kv_body(ctx, Wkvf, Kf, Vf, (int)(blockIdx.x - 512), smem);
}

// out-projection: 512 blocks
__global__ __launch_bounds__(256) void gemm_proj32(
    const float* __restrict__ A, const short* __restrict__ Wf,
    float* __restrict__ C, const float* __restrict__ bias)
{
    __shared__ __align__(16) char smem[32 * 72 * 2];
    proj32_body(A, Wf, C, bias, (int)(blockIdx.x >> 3), (int)(blockIdx.x & 7), smem);
}

// ---------------------------------------------------------------------------
// MFMA flash attention, 64-row q-tiles, 8 waves/block (512 threads).
// Block = (bh, 64 q-rows), 256 blocks = 1 block/CU = 8 waves/CU.
// Wave w owns 64-key chunks it*512 + w*64 (wave-private l via ones-MFMA);
// K-loop is barrier-free. S^T formulation, exp2-domain no-max softmax,
// P^T via quad shuffles. Epilogue: 8-wave merge into 2 LDS buffers
// (4 add phases), then combined normalize + store.
// ---------------------------------------------------------------------------
__global__ __launch_bounds__(512, 2) void attn_mfma(
    const float* __restrict__ Q,    // [2048, 512] fp32
    const short* __restrict__ Kfr,  // fragment-order K
    const short* __restrict__ Vfr,  // fragment-order V
    float* __restrict__ Og)         // [2048, 512] fp32
{
    __shared__ __align__(16) float Ob[2][64 * 66];   // 33.8 KB
    __shared__ float lbuf[8 * 64];

    const int bid = blockIdx.x;
    const int xcd = bid & 7, g = bid >> 3;
    const int bh  = xcd * 4 + (g & 3);     // 8 qt-blocks of one bh share bid%8
    const int qt  = g >> 2;                // 0..7 (64-row tiles)
    const int b   = bh >> 3, h = bh & 7;
    const int t   = threadIdx.x;
    const int w   = t >> 6, ln = t & 63;
    const int m16 = ln & 15, quad = ln >> 4;

    const short* Kbase = Kfr + (size_t)bh * (NM * DH);
    const short* Vbase = Vfr + (size_t)bh * (NM * DH);

    // Q scaled by (1/8) * log2(e)  -> scores in log2 domain
    const float qsc = 0.125f * 1.44269504f;
    bf16x8s qf[4][2];
    #pragma unroll
    for (int mt = 0; mt < 4; ++mt) {
        const float* qrow = Q + ((size_t)(b * NQ + qt * 64 + mt * 16 + m16)) * 512 + h * 64;
        #pragma unroll
        for (int ks = 0; ks < 2; ++ks) {
            float4 x0 = *(const float4*)(qrow + ks * 32 + quad * 8);
            float4 x1 = *(const float4*)(qrow + ks * 32 + quad * 8 + 4);
            uint4 pkv = { pk2(x0.x * qsc, x0.y * qsc), pk2(x0.z * qsc, x0.w * qsc),
                          pk2(x1.x * qsc, x1.y * qsc), pk2(x1.z * qsc, x1.w * qsc) };
            qf[mt][ks] = *reinterpret_cast<bf16x8s*>(&pkv);
        }
    }

    bf16x8s ones;
    #pragma unroll
    for (int j = 0; j < 8; ++j) ones[j] = (short)0x3F80;

    f32x4 o[4][4] = {};
    f32x4 lsum[4] = {};

    const int srcLo = (((quad << 1) & 3) << 4) + m16;
    const int srcHi = ((((quad << 1) + 1) & 3) << 4) + m16;
    const bool ktHi = quad >= 2;

    bf16x8s kf[4][2];
    {
        const int kc = w * 64;
        #pragma unroll
        for (int nt = 0; nt < 4; ++nt)
            #pragma unroll
            for (int ks = 0; ks < 2; ++ks)
                kf[nt][ks] = *(const bf16x8s*)(Kbase + ((((kc >> 4) + nt) * 2 + ks) << 9) + ln * 8);
    }

    for (int it = 0; it < 16; ++it) {
        const int kc = it * 512 + w * 64;

        bf16x8s vf[4][2];
        #pragma unroll
        for (int dt = 0; dt < 4; ++dt)
            #pragma unroll
            for (int ks = 0; ks < 2; ++ks)
                vf[dt][ks] = *(const bf16x8s*)(Vbase + ((dt * 256 + (kc >> 5) + ks) << 9) + ln * 8);

        f32x4 st[4][4] = {};
        #pragma unroll
        for (int kt = 0; kt < 4; ++kt)
            #pragma unroll
            for (int mt = 0; mt < 4; ++mt) {
                st[mt][kt] = __builtin_amdgcn_mfma_f32_16x16x32_bf16(kf[kt][0], qf[mt][0], st[mt][kt], 0, 0, 0);
                st[mt][kt] = __builtin_amdgcn_mfma_f32_16x16x32_bf16(kf[kt][1], qf[mt][1], st[mt][kt], 0, 0, 0);
            }

        if (it + 1 < 16) {
            const int kn = (it + 1) * 512 + w * 64;
            #pragma unroll
            for (int nt = 0; nt < 4; ++nt)
                #pragma unroll
                for (int ks = 0; ks < 2; ++ks)
                    kf[nt][ks] = *(const bf16x8s*)(Kbase + ((((kn >> 4) + nt) * 2 + ks) << 9) + ln * 8);
        }

        // p = 2^s, packed to bf16 pairs
        unsigned pp[4][4][2];
        #pragma unroll
        for (int mt = 0; mt < 4; ++mt)
            #pragma unroll
            for (int kt = 0; kt < 4; ++kt) {
                const float p0 = fexp2(st[mt][kt][0]);
                const float p1 = fexp2(st[mt][kt][1]);
                const float p2 = fexp2(st[mt][kt][2]);
                const float p3 = fexp2(st[mt][kt][3]);
                pp[mt][kt][0] = pk2(p0, p1);
                pp[mt][kt][1] = pk2(p2, p3);
            }

        // P^T -> B-frag via quad permutation; O^T += V^T @ P^T; l += 1 @ P^T
        #pragma unroll
        for (int mt = 0; mt < 4; ++mt)
            #pragma unroll
            for (int ks = 0; ks < 2; ++ks) {
                const unsigned a0 = __shfl(pp[mt][2 * ks][0], srcLo);
                const unsigned b0 = __shfl(pp[mt][2 * ks + 1][0], srcLo);
                const unsigned a1 = __shfl(pp[mt][2 * ks][1], srcLo);
                const unsigned b1 = __shfl(pp[mt][2 * ks + 1][1], srcLo);
                const unsigned a2 = __shfl(pp[mt][2 * ks][0], srcHi);
                const unsigned b2 = __shfl(pp[mt][2 * ks + 1][0], srcHi);
                const unsigned a3 = __shfl(pp[mt][2 * ks][1], srcHi);
                const unsigned b3 = __shfl(pp[mt][2 * ks + 1][1], srcHi);
                uint4 pb;
                pb.x = ktHi ? b0 : a0;
                pb.y = ktHi ? b1 : a1;
                pb.z = ktHi ? b2 : a2;
                pb.w = ktHi ? b3 : a3;
                bf16x8s pbv = *reinterpret_cast<bf16x8s*>(&pb);
                #pragma unroll
                for (int dt = 0; dt < 4; ++dt)
                    o[mt][dt] = __builtin_amdgcn_mfma_f32_16x16x32_bf16(vf[dt][ks], pbv, o[mt][dt], 0, 0, 0);
                lsum[mt] = __builtin_amdgcn_mfma_f32_16x16x32_bf16(ones, pbv, lsum[mt], 0, 0, 0);
            }
    }

    // ---- epilogue: l partials + 8-wave 2-buffer O merge ----
    if (quad == 0) {
        #pragma unroll
        for (int mt = 0; mt < 4; ++mt)
            lbuf[w * 64 + mt * 16 + m16] = lsum[mt][0];
    }
    // Phase A: waves 0,1 write buffers 0,1
    if (w < 2) {
        float* dst = Ob[w];
        #pragma unroll
        for (int mt = 0; mt < 4; ++mt)
            #pragma unroll
            for (int dt = 0; dt < 4; ++dt)
                *(f32x4*)&dst[(mt * 16 + m16) * 66 + dt * 16 + quad * 4] = o[mt][dt];
    }
    __syncthreads();
    // Phases B..D: waves {2,3}, {4,5}, {6,7} add into buffers 0,1
    #pragma unroll
    for (int ph = 1; ph < 4; ++ph) {
        if ((w >> 1) == ph) {
            float* dst = Ob[w & 1];
            #pragma unroll
            for (int mt = 0; mt < 4; ++mt)
                #pragma unroll
                for (int dt = 0; dt < 4; ++dt) {
                    float* p = &dst[(mt * 16 + m16) * 66 + dt * 16 + quad * 4];
                    f32x4 cur = *(f32x4*)p;
                    cur += o[mt][dt];
                    *(f32x4*)p = cur;
                }
        }
        __syncthreads();
    }
    // Final: combine the two buffers, normalize, store (512 threads)
    {
        const int row = t >> 3;             // 0..63
        const int d0  = (t & 7) << 3;       // 8 floats per thread
        float l = 0.f;
        #pragma unroll
        for (int wi = 0; wi < 8; ++wi) l += lbuf[wi * 64 + row];
        const float inv = 1.0f / l;
        float* op = Og + ((size_t)(b * NQ + qt * 64 + row)) * 512 + h * 64 + d0;
        #pragma unroll
        for (int j = 0; j < 2; ++j) {
            const int c = row * 66 + d0 + j * 4;
            float4 r;
            r.x = (Ob[0][c + 0] + Ob[1][c + 0]) * inv;
            r.y = (Ob[0][c + 1] + Ob[1][c + 1]) * inv;
            r.z = (Ob[0][c + 2] + Ob[1][c + 2]) * inv;
            r.w = (Ob[0][c + 3] + Ob[1][c + 3]) * inv;
            *(float4*)(op + j * 4) = r;
        }
    }
}

// ---------------------------------------------------------------------------
extern "C" void kernel_launch(void* const* d_in, const int* in_sizes, int n_in,
                              void* d_out, int out_size, void* d_ws, size_t ws_size,
                              hipStream_t stream) {
    (void)in_sizes; (void)n_in; (void)out_size; (void)ws_size;

    const float* x   = (const float*)d_in[0];   // [4, 512, 512]
    const float* ctx = (const float*)d_in[1];   // [4, 8192, 256]
    const float* Wq  = (const float*)d_in[2];   // [512, 512]
    const float* Wkv = (const float*)d_in[3];   // [256, 1024]
    const float* Wo  = (const float*)d_in[4];   // [512, 512]
    const float* bo  = (const float*)d_in[5];   // [512]
    float* out = (float*)d_out;                 // [4, 512, 512]

    float* ws    = (float*)d_ws;
    float* q     = ws;                                       // 4 MB fp32
    float* attno = q + (size_t)2048 * 512;                   // 4 MB fp32
    short* Kf    = (short*)(attno + (size_t)2048 * 512);     // 33.5 MB bf16 (fragment order)
    short* Vf    = Kf + (size_t)NB * NH * NM * DH;           // 33.5 MB bf16 (fragment order)
    short* Wqf   = Vf + (size_t)NB * NH * NM * DH;           // 512 KB
    short* Wof   = Wqf + (size_t)512 * 512;                  // 512 KB
    short* Wkvf  = Wof + (size_t)512 * 512;                  // 512 KB

    // weights -> bf16 fragment order
    prep_weights<<<dim3(384), dim3(256), 0, stream>>>(Wq, Wo, Wkv, Wqf, Wof, Wkvf);

    // q = x@Wq (512 blocks) + kv = ctx@Wkv (2048 blocks) in one launch
    gemm_kvq<<<dim3(2560), dim3(256), 0, stream>>>(x, Wqf, q, ctx, Wkvf, Kf, Vf);

    // flash attention: 32 bh x 8 q-tiles = 256 blocks x 512 threads (8 waves/CU)
    attn_mfma<<<dim3(256), dim3(512), 0, stream>>>(q, Kf, Vf, attno);

    // out = attno @ Wo + bo (512 blocks)
    gemm_proj32<<<dim3(512), dim3(256), 0, stream>>>(attno, Wof, out, bo);
}

// Round 12
// 186.154 us; speedup vs baseline: 1.4055x; 1.0184x over previous
//
#include <hip/hip_runtime.h>
#include <hip/hip_bf16.h>
#include <cstdint>

#define NB 4
#define NQ 512
#define NM 8192
#define NH 8
#define DH 64

typedef short bf16x8s __attribute__((ext_vector_type(8)));
typedef short bf16x4s __attribute__((ext_vector_type(4)));
typedef float f32x4  __attribute__((ext_vector_type(4)));

// fast fp32->bf16 (round-half-up)
static __device__ __forceinline__ short f2bs(float f) {
    unsigned u = __builtin_bit_cast(unsigned, f);
    return (short)(unsigned short)((u + 0x8000u) >> 16);
}
// packed pair via v_perm_b32: lo16 = bf16(a), hi16 = bf16(b)
static __device__ __forceinline__ unsigned pk2(float a, float b) {
    unsigned au = __builtin_bit_cast(unsigned, a) + 0x8000u;
    unsigned bu = __builtin_bit_cast(unsigned, b) + 0x8000u;
    return __builtin_amdgcn_perm(bu, au, 0x07060302u);
}

#if __has_builtin(__builtin_amdgcn_exp2f)
static __device__ __forceinline__ float fexp2(float x) { return __builtin_amdgcn_exp2f(x); }
#else
static __device__ __forceinline__ float fexp2(float x) { return exp2f(x); }
#endif

// ---------------------------------------------------------------------------
// Weight prep: Wq/Wo [512,512], Wkv [256,1024] (fp32 [k][n]) -> bf16 MFMA
// B-fragment order: Wf[(n0*KS + ks)*64 + lane][j] = W[ks*32+quad*8+j][n0*16+m16]
// ---------------------------------------------------------------------------
__global__ __launch_bounds__(256) void prep_weights(
    const float* __restrict__ Wq, const float* __restrict__ Wo,
    const float* __restrict__ Wkv,
    short* __restrict__ Wqf, short* __restrict__ Wof, short* __restrict__ Wkvf)
{
    const int t = threadIdx.x;
    const int w = t >> 6, ln = t & 63;
    const int m16 = ln & 15, quad = ln >> 4;
    int f = blockIdx.x * 4 + w;           // 0..1535
    const float* src; short* dst; int N, KS, n0, ks;
    if (f < 512)       { src = Wq;  dst = Wqf;  N = 512;  KS = 16; n0 = f >> 4; ks = f & 15; }
    else if (f < 1024) { f -= 512;  src = Wo;  dst = Wof;  N = 512;  KS = 16; n0 = f >> 4; ks = f & 15; }
    else               { f -= 1024; src = Wkv; dst = Wkvf; N = 1024; KS = 8;  n0 = f >> 3; ks = f & 7; }
    const float* sp = src + (size_t)(ks * 32 + quad * 8) * N + n0 * 16 + m16;
    float v[8];
    #pragma unroll
    for (int j = 0; j < 8; ++j) v[j] = sp[(size_t)j * N];
    uint4 pkv = { pk2(v[0],v[1]), pk2(v[2],v[3]), pk2(v[4],v[5]), pk2(v[6],v[7]) };
    *(uint4*)(dst + ((size_t)(n0 * KS + ks) * 64 + ln) * 8) = pkv;
}

// ---------------------------------------------------------------------------
// Projection GEMM body: C = A[2048,512] @ W[512,512] (+bias).
// 32x64 tile, BK=64; A via LDS staging, B-frags direct from frag-order
// weights. 512 blocks.
// ---------------------------------------------------------------------------
__device__ __forceinline__ void proj32_body(
    const float* __restrict__ A, const short* __restrict__ Wf,
    float* __restrict__ C, const float* __restrict__ bias,
    int tm, int tn, char* smemraw)
{
    short* As = (short*)smemraw;        // [32][72]

    const int t = threadIdx.x;
    const int w = t >> 6, ln = t & 63;
    const int m16 = ln & 15, quad = ln >> 4;
    const int wm = w >> 1, wn = w & 1;

    const int ar = t >> 3, ac = (t & 7) << 3;      // A: 32 rows x 64 k

    const float* Ap = A + (size_t)(tm * 32 + ar) * 512 + ac;

    f32x4 acc[2] = {};

    for (int k0 = 0; k0 < 512; k0 += 64) {
        float4 a0 = *(const float4*)(Ap + k0);
        float4 a1 = *(const float4*)(Ap + k0 + 4);
        bf16x8s bfr[2][2];
        #pragma unroll
        for (int ks = 0; ks < 2; ++ks)
            #pragma unroll
            for (int nt = 0; nt < 2; ++nt)
                bfr[ks][nt] = *(const bf16x8s*)(Wf +
                    ((size_t)((tn * 4 + wn * 2 + nt) * 16 + (k0 >> 5) + ks) * 64 + ln) * 8);

        __syncthreads();
        {
            uint4 wa = { pk2(a0.x,a0.y), pk2(a0.z,a0.w), pk2(a1.x,a1.y), pk2(a1.z,a1.w) };
            *(uint4*)&As[ar * 72 + ac] = wa;
        }
        __syncthreads();

        #pragma unroll
        for (int ks = 0; ks < 2; ++ks) {
            bf16x8s af = *(const bf16x8s*)&As[(wm * 16 + m16) * 72 + ks * 32 + quad * 8];
            #pragma unroll
            for (int nt = 0; nt < 2; ++nt)
                acc[nt] = __builtin_amdgcn_mfma_f32_16x16x32_bf16(af, bfr[ks][nt], acc[nt], 0, 0, 0);
        }
    }

    const int row0 = tm * 32 + wm * 16 + quad * 4;
    const int col0 = tn * 64 + wn * 32;
    #pragma unroll
    for (int nt = 0; nt < 2; ++nt) {
        const int col = col0 + nt * 16 + m16;
        const float bb = bias ? bias[col] : 0.f;
        #pragma unroll
        for (int r = 0; r < 4; ++r)
            C[(size_t)(row0 + r) * 512 + col] = acc[nt][r] + bb;
    }
}

// ---------------------------------------------------------------------------
// kv GEMM body: 128x128 tile, BK=32, K=256; A via LDS, B-frags direct from
// frag-order Wkv.
// K epilogue: fragment order for 16x16x32 B-operand (QK^T).
// V epilogue: fragment order for 16x16x16 A-operand (PV), two 16-key tiles
//             per b128: Vf[bh][dt][ktpair][lane=quad*16+d16][kt0:k=quad*4+i | kt1:...]
// ---------------------------------------------------------------------------
__device__ __forceinline__ void kv_body(
    const float* __restrict__ A, const short* __restrict__ Wkvf,
    short* __restrict__ Kf, short* __restrict__ Vf,
    int kvid, char* smemraw)
{
    short* As = (short*)smemraw;        // [128][40]

    const int t  = threadIdx.x;
    // temporal+XCD swizzle: 8 n-tiles of one m-tile are 8 consecutive slots
    // on the same XCD (kvid&7 == XCD of block since kv blocks start at 512)
    const int tm = ((kvid >> 6) << 3) | (kvid & 7);
    const int tn = (kvid >> 3) & 7;
    const int w  = t >> 6, ln = t & 63;
    const int m16 = ln & 15, quad = ln >> 4;
    const int wm = w & 1, wn = w >> 1;

    const int ar = t >> 3;
    const int ac = (t & 7) << 2;

    const float* Abase = A + (size_t)(tm * 128 + ar) * 256 + ac;

    f32x4 acc[4][4] = {};

    for (int k0 = 0; k0 < 256; k0 += 32) {
        float4 av[4];
        #pragma unroll
        for (int p = 0; p < 4; ++p)
            av[p] = *(const float4*)(Abase + (size_t)p * 32 * 256 + k0);
        bf16x8s bfr[4];
        #pragma unroll
        for (int j = 0; j < 4; ++j)
            bfr[j] = *(const bf16x8s*)(Wkvf +
                ((size_t)((tn * 8 + wn * 4 + j) * 8 + (k0 >> 5)) * 64 + ln) * 8);

        __syncthreads();
        #pragma unroll
        for (int p = 0; p < 4; ++p) {
            uint2 wv = { pk2(av[p].x, av[p].y), pk2(av[p].z, av[p].w) };
            *(uint2*)&As[(p * 32 + ar) * 40 + ac] = wv;
        }
        __syncthreads();

        bf16x8s af[4];
        #pragma unroll
        for (int i = 0; i < 4; ++i)
            af[i] = *(const bf16x8s*)&As[(wm * 64 + i * 16 + m16) * 40 + quad * 8];
        #pragma unroll
        for (int i = 0; i < 4; ++i)
            #pragma unroll
            for (int j = 0; j < 4; ++j)
                acc[i][j] = __builtin_amdgcn_mfma_f32_16x16x32_bf16(af[i], bfr[j], acc[i][j], 0, 0, 0);
    }

    const int col0 = tn * 128 + wn * 64;
    const int row0 = tm * 128 + wm * 64;
    const int b    = row0 >> 13;
    const int mr0  = row0 & (NM - 1);

    if (col0 < 512) {
        const int h = col0 >> 6;
        short* Kp = Kf + (size_t)(b * NH + h) * (NM * DH);
        #pragma unroll
        for (int i = 0; i < 4; ++i)
            #pragma unroll
            for (int j = 0; j < 4; ++j) {
                const int d = j * 16 + m16;
                #pragma unroll
                for (int r = 0; r < 4; ++r) {
                    const int key = mr0 + i * 16 + quad * 4 + r;
                    const int idx = ((key >> 4) * 2 + (d >> 5)) * 512
                                  + (((d >> 3) & 3) * 16 + (key & 15)) * 8 + (d & 7);
                    Kp[idx] = f2bs(acc[i][j][r]);
                }
            }
    } else {
        // V: acc[i][j][r] = V[key = mr0+i*16+quad*4+r][d = j*16+m16]
        // Producer lane (quad,m16) == consumer lane (k-quad, d16): write own slot.
        const int h = (col0 - 512) >> 6;
        short* Vp = Vf + (size_t)(b * NH + h) * (NM * DH);
        #pragma unroll
        for (int j = 0; j < 4; ++j)
            #pragma unroll
            for (int p = 0; p < 2; ++p) {
                uint4 v;
                v.x = pk2(acc[2*p    ][j][0], acc[2*p    ][j][1]);
                v.y = pk2(acc[2*p    ][j][2], acc[2*p    ][j][3]);
                v.z = pk2(acc[2*p + 1][j][0], acc[2*p + 1][j][1]);
                v.w = pk2(acc[2*p + 1][j][2], acc[2*p + 1][j][3]);
                *(uint4*)(Vp + ((size_t)(j * 256 + (mr0 >> 5) + p) * 64 + ln) * 8) = v;
            }
    }
}

// ---------------------------------------------------------------------------
// Uber kernel: blocks 0..511 do q = x@Wq (proj32), blocks 512..2559 do kv.
// ---------------------------------------------------------------------------
__global__ __launch_bounds__(256) void gemm_kvq(
    const float* __restrict__ x,   const short* __restrict__ Wqf, float* __restrict__ q,
    const float* __restrict__ ctx, const short* __restrict__ Wkvf,
    short* __restrict__ Kf, short* __restrict__ Vf)
{
    __shared__ __align__(16) char smem[10240];
    if (blockIdx.x < 512)
        proj32_body(x, Wqf, q, nullptr, (int)(blockIdx.x >> 3), (int)(blockIdx.x & 7), smem);
    else
        kv_body(ctx, Wkvf, Kf, Vf, (int)(blockIdx.x - 512), smem);
}

// out-projection: 512 blocks
__global__ __launch_bounds__(256) void gemm_proj32(
    const float* __restrict__ A, const short* __restrict__ Wf,
    float* __restrict__ C, const float* __restrict__ bias)
{
    __shared__ __align__(16) char smem[32 * 72 * 2];
    proj32_body(A, Wf, C, bias, (int)(blockIdx.x >> 3), (int)(blockIdx.x & 7), smem);
}

// ---------------------------------------------------------------------------
// MFMA flash attention, 64-row q-tiles, 8 waves/block (512 threads).
// S^T via 16x16x32 (B = Q frag). PV via 16x16x16: the C-layout of S^T
// (key=quad*4+r, q=m16) IS the B-operand layout of the K=16 MFMA
// (k=quad*4+i, n=lane%16) -> P^T feeds PV directly, ZERO cross-lane ops.
// V loaded as K=16 A-operand fragments (two 16-key tiles per b128).
// l via ones-MFMA. Barrier-free K-loop; 8-wave LDS merge epilogue.
// ---------------------------------------------------------------------------
__global__ __launch_bounds__(512, 2) void attn_mfma(
    const float* __restrict__ Q,    // [2048, 512] fp32
    const short* __restrict__ Kfr,  // fragment-order K (16x16x32 B-op)
    const short* __restrict__ Vfr,  // fragment-order V (16x16x16 A-op)
    float* __restrict__ Og)         // [2048, 512] fp32
{
    __shared__ __align__(16) float Ob[2][64 * 66];   // 33.8 KB
    __shared__ float lbuf[8 * 64];

    const int bid = blockIdx.x;
    const int xcd = bid & 7, g = bid >> 3;
    const int bh  = xcd * 4 + (g & 3);     // 8 qt-blocks of one bh share bid%8
    const int qt  = g >> 2;                // 0..7 (64-row tiles)
    const int b   = bh >> 3, h = bh & 7;
    const int t   = threadIdx.x;
    const int w   = t >> 6, ln = t & 63;
    const int m16 = ln & 15, quad = ln >> 4;

    const short* Kbase = Kfr + (size_t)bh * (NM * DH);
    const short* Vbase = Vfr + (size_t)bh * (NM * DH);

    // Q scaled by (1/8) * log2(e)  -> scores in log2 domain
    const float qsc = 0.125f * 1.44269504f;
    bf16x8s qf[4][2];
    #pragma unroll
    for (int mt = 0; mt < 4; ++mt) {
        const float* qrow = Q + ((size_t)(b * NQ + qt * 64 + mt * 16 + m16)) * 512 + h * 64;
        #pragma unroll
        for (int ks = 0; ks < 2; ++ks) {
            float4 x0 = *(const float4*)(qrow + ks * 32 + quad * 8);
            float4 x1 = *(const float4*)(qrow + ks * 32 + quad * 8 + 4);
            uint4 pkv = { pk2(x0.x * qsc, x0.y * qsc), pk2(x0.z * qsc, x0.w * qsc),
                          pk2(x1.x * qsc, x1.y * qsc), pk2(x1.z * qsc, x1.w * qsc) };
            qf[mt][ks] = *reinterpret_cast<bf16x8s*>(&pkv);
        }
    }

    bf16x4s ones4;
    #pragma unroll
    for (int j = 0; j < 4; ++j) ones4[j] = (short)0x3F80;

    f32x4 o[4][4] = {};
    f32x4 lsum[4] = {};

    bf16x8s kf[4][2];
    {
        const int kc = w * 64;
        #pragma unroll
        for (int nt = 0; nt < 4; ++nt)
            #pragma unroll
            for (int ks = 0; ks < 2; ++ks)
                kf[nt][ks] = *(const bf16x8s*)(Kbase + ((((kc >> 4) + nt) * 2 + ks) << 9) + ln * 8);
    }

    for (int it = 0; it < 16; ++it) {
        const int kc = it * 512 + w * 64;

        // V frags: b128 per (dt, ktpair); halves are K=16 A-operands
        uint4 vraw[4][2];
        #pragma unroll
        for (int dt = 0; dt < 4; ++dt)
            #pragma unroll
            for (int kp = 0; kp < 2; ++kp)
                vraw[dt][kp] = *(const uint4*)(Vbase + ((size_t)(dt * 256 + (kc >> 5) + kp) * 64 + ln) * 8);

        // S^T : 16x16x32, C-layout key=quad*4+r (within kt tile), q=m16
        f32x4 st[4][4] = {};
        #pragma unroll
        for (int kt = 0; kt < 4; ++kt)
            #pragma unroll
            for (int mt = 0; mt < 4; ++mt) {
                st[mt][kt] = __builtin_amdgcn_mfma_f32_16x16x32_bf16(kf[kt][0], qf[mt][0], st[mt][kt], 0, 0, 0);
                st[mt][kt] = __builtin_amdgcn_mfma_f32_16x16x32_bf16(kf[kt][1], qf[mt][1], st[mt][kt], 0, 0, 0);
            }

        if (it + 1 < 16) {
            const int kn = (it + 1) * 512 + w * 64;
            #pragma unroll
            for (int nt = 0; nt < 4; ++nt)
                #pragma unroll
                for (int ks = 0; ks < 2; ++ks)
                    kf[nt][ks] = *(const bf16x8s*)(Kbase + ((((kn >> 4) + nt) * 2 + ks) << 9) + ln * 8);
        }

        // p = 2^s, pack -> K=16 B-operand directly (no cross-lane ops!)
        #pragma unroll
        for (int mt = 0; mt < 4; ++mt)
            #pragma unroll
            for (int kt = 0; kt < 4; ++kt) {
                const float p0 = fexp2(st[mt][kt][0]);
                const float p1 = fexp2(st[mt][kt][1]);
                const float p2 = fexp2(st[mt][kt][2]);
                const float p3 = fexp2(st[mt][kt][3]);
                uint2 pu = { pk2(p0, p1), pk2(p2, p3) };
                bf16x4s pbv = *reinterpret_cast<bf16x4s*>(&pu);
                const int kp = kt >> 1, hh = kt & 1;
                #pragma unroll
                for (int dt = 0; dt < 4; ++dt) {
                    uint2 vh = hh ? make_uint2(vraw[dt][kp].z, vraw[dt][kp].w)
                                  : make_uint2(vraw[dt][kp].x, vraw[dt][kp].y);
                    bf16x4s va = *reinterpret_cast<bf16x4s*>(&vh);
                    o[mt][dt] = __builtin_amdgcn_mfma_f32_16x16x16bf16_1k(va, pbv, o[mt][dt], 0, 0, 0);
                }
                lsum[mt] = __builtin_amdgcn_mfma_f32_16x16x16bf16_1k(ones4, pbv, lsum[mt], 0, 0, 0);
            }
    }

    // ---- epilogue: l partials + 8-wave 2-buffer O merge ----
    if (quad == 0) {
        #pragma unroll
        for (int mt = 0; mt < 4; ++mt)
            lbuf[w * 64 + mt * 16 + m16] = lsum[mt][0];
    }
    // Phase A: waves 0,1 write buffers 0,1
    if (w < 2) {
        float* dst = Ob[w];
        #pragma unroll
        for (int mt = 0; mt < 4; ++mt)
            #pragma unroll
            for (int dt = 0; dt < 4; ++dt)
                *(f32x4*)&dst[(mt * 16 + m16) * 66 + dt * 16 + quad * 4] = o[mt][dt];
    }
    __syncthreads();
    // Phases B..D: waves {2,3}, {4,5}, {6,7} add into buffers 0,1
    #pragma unroll
    for (int ph = 1; ph < 4; ++ph) {
        if ((w >> 1) == ph) {
            float* dst = Ob[w & 1];
            #pragma unroll
            for (int mt = 0; mt < 4; ++mt)
                #pragma unroll
                for (int dt = 0; dt < 4; ++dt) {
                    float* p = &dst[(mt * 16 + m16) * 66 + dt * 16 + quad * 4];
                    f32x4 cur = *(f32x4*)p;
                    cur += o[mt][dt];
                    *(f32x4*)p = cur;
                }
        }
        __syncthreads();
    }
    // Final: combine the two buffers, normalize, store (512 threads)
    {
        const int row = t >> 3;             // 0..63
        const int d0  = (t & 7) << 3;       // 8 floats per thread
        float l = 0.f;
        #pragma unroll
        for (int wi = 0; wi < 8; ++wi) l += lbuf[wi * 64 + row];
        const float inv = 1.0f / l;
        float* op = Og + ((size_t)(b * NQ + qt * 64 + row)) * 512 + h * 64 + d0;
        #pragma unroll
        for (int j = 0; j < 2; ++j) {
            const int c = row * 66 + d0 + j * 4;
            float4 r;
            r.x = (Ob[0][c + 0] + Ob[1][c + 0]) * inv;
            r.y = (Ob[0][c + 1] + Ob[1][c + 1]) * inv;
            r.z = (Ob[0][c + 2] + Ob[1][c + 2]) * inv;
            r.w = (Ob[0][c + 3] + Ob[1][c + 3]) * inv;
            *(float4*)(op + j * 4) = r;
        }
    }
}

// ---------------------------------------------------------------------------
extern "C" void kernel_launch(void* const* d_in, const int* in_sizes, int n_in,
                              void* d_out, int out_size, void* d_ws, size_t ws_size,
                              hipStream_t stream) {
    (void)in_sizes; (void)n_in; (void)out_size; (void)ws_size;

    const float* x   = (const float*)d_in[0];   // [4, 512, 512]
    const float* ctx = (const float*)d_in[1];   // [4, 8192, 256]
    const float* Wq  = (const float*)d_in[2];   // [512, 512]
    const float* Wkv = (const float*)d_in[3];   // [256, 1024]
    const float* Wo  = (const float*)d_in[4];   // [512, 512]
    const float* bo  = (const float*)d_in[5];   // [512]
    float* out = (float*)d_out;                 // [4, 512, 512]

    float* ws    = (float*)d_ws;
    float* q     = ws;                                       // 4 MB fp32
    float* attno = q + (size_t)2048 * 512;                   // 4 MB fp32
    short* Kf    = (short*)(attno + (size_t)2048 * 512);     // 33.5 MB bf16 (fragment order)
    short* Vf    = Kf + (size_t)NB * NH * NM * DH;           // 33.5 MB bf16 (fragment order)
    short* Wqf   = Vf + (size_t)NB * NH * NM * DH;           // 512 KB
    short* Wof   = Wqf + (size_t)512 * 512;                  // 512 KB
    short* Wkvf  = Wof + (size_t)512 * 512;                  // 512 KB

    // weights -> bf16 fragment order
    prep_weights<<<dim3(384), dim3(256), 0, stream>>>(Wq, Wo, Wkv, Wqf, Wof, Wkvf);

    // q = x@Wq (512 blocks) + kv = ctx@Wkv (2048 blocks) in one launch
    gemm_kvq<<<dim3(2560), dim3(256), 0, stream>>>(x, Wqf, q, ctx, Wkvf, Kf, Vf);

    // flash attention: 32 bh x 8 q-tiles = 256 blocks x 512 threads (8 waves/CU)
    attn_mfma<<<dim3(256), dim3(512), 0, stream>>>(q, Kf, Vf, attno);

    // out = attno @ Wo + bo (512 blocks)
    gemm_proj32<<<dim3(512), dim3(256), 0, stream>>>(attno, Wof, out, bo);
}